// Round 1
// baseline (264.297 us; speedup 1.0000x reference)
//
#include <hip/hip_runtime.h>
#include <stdint.h>

typedef unsigned short u16;
typedef float f32x4 __attribute__((ext_vector_type(4)));
typedef __bf16 bf16x8 __attribute__((ext_vector_type(8)));

#define AS1 __attribute__((address_space(1)))
#define AS3 __attribute__((address_space(3)))

__device__ __forceinline__ u16 f32_to_bf16(float f) {
    unsigned u = __float_as_uint(f);
    unsigned r = u + 0x7fffu + ((u >> 16) & 1u);
    return (u16)(r >> 16);
}

__device__ __forceinline__ void gload_lds16(const u16* g, u16* l) {
    __builtin_amdgcn_global_load_lds((const AS1 unsigned int*)g,
                                     (AS3 unsigned int*)l, 16, 0, 0);
}

// element offset into a [rows][64]-u16 tile, XOR-swizzled at 16B-chunk granularity
__device__ __forceinline__ int swz(int row, int col8) {
    return row * 64 + (((col8 ^ (row & 7)) & 7) << 3);
}

// ---------------- f32 -> bf16 convert ----------------
__global__ __launch_bounds__(256) void cvt_bf16(const float4* __restrict__ in,
                                                uint2* __restrict__ out, int n4) {
    for (int i = blockIdx.x * blockDim.x + threadIdx.x; i < n4;
         i += gridDim.x * blockDim.x) {
        float4 v = in[i];
        uint2 o;
        o.x = (unsigned)f32_to_bf16(v.x) | ((unsigned)f32_to_bf16(v.y) << 16);
        o.y = (unsigned)f32_to_bf16(v.z) | ((unsigned)f32_to_bf16(v.w) << 16);
        out[i] = o;
    }
}

// ---------------- C[M,N] = A[M,K] * B[N,K]^T + bias ----------------
// A, B bf16 row-major with K contiguous. 128x128 tile, BK=64, 4 waves (2x2).
template <bool BF16_OUT>
__global__ __launch_bounds__(256) void gemm_bt(const u16* __restrict__ A,
                                               const u16* __restrict__ B,
                                               const float* __restrict__ bias,
                                               void* __restrict__ Cv,
                                               int M, int N, int K) {
    __shared__ u16 As[128 * 64];
    __shared__ u16 Bs[128 * 64];
    const int t = threadIdx.x;
    const int w = t >> 6, l = t & 63;
    const int lr = l & 15, lhi = l >> 4;
    const int wm = (w >> 1) * 64, wn = (w & 1) * 64;
    const int bm = blockIdx.x, bn = blockIdx.y;

    const u16* Ag = A + (size_t)bm * 128 * K;
    const u16* Bg = B + (size_t)bn * 128 * K;

    f32x4 acc[4][4] = {};

    for (int k0 = 0; k0 < K; k0 += 64) {
        // stage A,B tiles: [128][64] bf16 each = 1024 16B chunks / tile
        #pragma unroll
        for (int i = 0; i < 4; ++i) {
            int c = i * 256 + t;
            int r = c >> 3, cl = c & 7;
            gload_lds16(Ag + (size_t)r * K + k0 + ((cl ^ (r & 7)) << 3), As + c * 8);
        }
        #pragma unroll
        for (int i = 0; i < 4; ++i) {
            int c = i * 256 + t;
            int r = c >> 3, cl = c & 7;
            gload_lds16(Bg + (size_t)r * K + k0 + ((cl ^ (r & 7)) << 3), Bs + c * 8);
        }
        asm volatile("s_waitcnt vmcnt(0)" ::: "memory");
        __syncthreads();

        #pragma unroll
        for (int kks = 0; kks < 2; ++kks) {
            bf16x8 af[4], bfv[4];
            #pragma unroll
            for (int m = 0; m < 4; ++m)
                af[m] = *(const bf16x8*)(As + swz(wm + m * 16 + lr, kks * 4 + lhi));
            #pragma unroll
            for (int n = 0; n < 4; ++n)
                bfv[n] = *(const bf16x8*)(Bs + swz(wn + n * 16 + lr, kks * 4 + lhi));
            #pragma unroll
            for (int m = 0; m < 4; ++m)
                #pragma unroll
                for (int n = 0; n < 4; ++n)
                    acc[m][n] = __builtin_amdgcn_mfma_f32_16x16x32_bf16(
                        af[m], bfv[n], acc[m][n], 0, 0, 0);
        }
        __syncthreads();
    }

    const int row0 = bm * 128 + wm + lhi * 4;
    const int col0 = bn * 128 + wn + lr;
    #pragma unroll
    for (int n = 0; n < 4; ++n) {
        int col = col0 + n * 16;
        float bv = bias[col];
        #pragma unroll
        for (int m = 0; m < 4; ++m) {
            #pragma unroll
            for (int r = 0; r < 4; ++r) {
                int row = row0 + m * 16 + r;
                float v = acc[m][n][r] + bv;
                if constexpr (BF16_OUT)
                    ((u16*)Cv)[(size_t)row * N + col] = f32_to_bf16(v);
                else
                    ((float*)Cv)[(size_t)row * N + col] = v;
            }
        }
    }
}

// ---------------- causal flash attention ----------------
// qkv: [B*S][3072] bf16 (q|k|v each [.,H=16,Dh=64]); out: [B*S][1024] bf16
// grid: (S/64, H, B); 4 waves, wave w owns q rows [w*16, w*16+16) of the tile.
__global__ __launch_bounds__(256) void attn_kernel(const u16* __restrict__ qkv,
                                                   u16* __restrict__ out) {
    __shared__ u16 Qs[64 * 64];
    __shared__ u16 Ks[64 * 64];
    __shared__ u16 Vt[64 * 64];   // transposed: [dh][k]
    __shared__ u16 Ps[4 * 16 * 64];
    const int t = threadIdx.x;
    const int w = t >> 6, l = t & 63;
    const int lr = l & 15, lhi = l >> 4;
    const int qt = blockIdx.x, h = blockIdx.y, b = blockIdx.z;

    const u16* Qg = qkv + ((size_t)(b * 2048 + qt * 64)) * 3072 + h * 64;
    const u16* Kg = qkv + ((size_t)(b * 2048)) * 3072 + 1024 + h * 64;
    const u16* Vg = qkv + ((size_t)(b * 2048)) * 3072 + 2048 + h * 64;

    // stage Q tile [64][64] (swizzled)
    #pragma unroll
    for (int i = 0; i < 2; ++i) {
        int c = i * 256 + t;
        int r = c >> 3, cl = c & 7;
        gload_lds16(Qg + (size_t)r * 3072 + ((cl ^ (r & 7)) << 3), Qs + c * 8);
    }
    asm volatile("s_waitcnt vmcnt(0)" ::: "memory");
    __syncthreads();

    bf16x8 qf[2];
    #pragma unroll
    for (int kks = 0; kks < 2; ++kks)
        qf[kks] = *(const bf16x8*)(Qs + swz(w * 16 + lr, kks * 4 + lhi));

    u16* Pw = Ps + w * 16 * 64;
    f32x4 acc[4] = {};
    float m_run[4] = {-1e30f, -1e30f, -1e30f, -1e30f};
    float l_run[4] = {0.f, 0.f, 0.f, 0.f};
    const float SCALE = 0.125f * 1.44269504088896340736f;  // 1/sqrt(64) * log2(e)

    for (int t64 = 0; t64 <= qt; ++t64) {
        __syncthreads();  // previous tile fully consumed before restaging
        // stage K tile [64][64] (swizzled)
        #pragma unroll
        for (int i = 0; i < 2; ++i) {
            int c = i * 256 + t;
            int r = c >> 3, cl = c & 7;
            gload_lds16(Kg + ((size_t)(t64 * 64 + r)) * 3072 + ((cl ^ (r & 7)) << 3),
                        Ks + c * 8);
        }
        // stage V transposed via registers (swizzled scalar writes)
        #pragma unroll
        for (int i = 0; i < 2; ++i) {
            int c = i * 256 + t;
            int r = c >> 3, cl = c & 7;
            uint4 d = *(const uint4*)(Vg + ((size_t)(t64 * 64 + r)) * 3072 + cl * 8);
            unsigned dw[4] = {d.x, d.y, d.z, d.w};
            #pragma unroll
            for (int j = 0; j < 8; ++j) {
                int dh = cl * 8 + j;
                Vt[swz(dh, r >> 3) + (r & 7)] = (u16)(dw[j >> 1] >> ((j & 1) * 16));
            }
        }
        asm volatile("s_waitcnt vmcnt(0)" ::: "memory");
        __syncthreads();

        // S = Q K^T  (per wave: 16 q-rows x 64 kv)
        f32x4 sv[4] = {};
        #pragma unroll
        for (int kks = 0; kks < 2; ++kks) {
            #pragma unroll
            for (int n = 0; n < 4; ++n) {
                bf16x8 kf = *(const bf16x8*)(Ks + swz(n * 16 + lr, kks * 4 + lhi));
                sv[n] = __builtin_amdgcn_mfma_f32_16x16x32_bf16(qf[kks], kf, sv[n], 0, 0, 0);
            }
        }

        // scale + causal mask + row max
        const bool diag = (t64 == qt);
        float mx[4] = {-1e30f, -1e30f, -1e30f, -1e30f};
        #pragma unroll
        for (int n = 0; n < 4; ++n)
            #pragma unroll
            for (int r = 0; r < 4; ++r) {
                float v = sv[n][r] * SCALE;
                if (diag && (n * 16 + lr) > (w * 16 + lhi * 4 + r)) v = -1e30f;
                sv[n][r] = v;
                mx[r] = fmaxf(mx[r], v);
            }
        #pragma unroll
        for (int off = 1; off < 16; off <<= 1)
            #pragma unroll
            for (int r = 0; r < 4; ++r)
                mx[r] = fmaxf(mx[r], __shfl_xor(mx[r], off, 64));

        float alpha[4], rs[4];
        #pragma unroll
        for (int r = 0; r < 4; ++r) {
            float mn = fmaxf(m_run[r], mx[r]);
            alpha[r] = exp2f(m_run[r] - mn);
            m_run[r] = mn;
            rs[r] = 0.f;
        }
        // P = exp2(s - m), staged to per-wave LDS in A-fragment layout
        #pragma unroll
        for (int n = 0; n < 4; ++n)
            #pragma unroll
            for (int r = 0; r < 4; ++r) {
                float p = exp2f(sv[n][r] - m_run[r]);
                rs[r] += p;
                int col = n * 16 + lr;
                Pw[swz(lhi * 4 + r, col >> 3) + (col & 7)] = f32_to_bf16(p);
            }
        #pragma unroll
        for (int off = 1; off < 16; off <<= 1)
            #pragma unroll
            for (int r = 0; r < 4; ++r)
                rs[r] += __shfl_xor(rs[r], off, 64);
        #pragma unroll
        for (int r = 0; r < 4; ++r)
            l_run[r] = l_run[r] * alpha[r] + rs[r];
        #pragma unroll
        for (int n = 0; n < 4; ++n)
            #pragma unroll
            for (int r = 0; r < 4; ++r)
                acc[n][r] *= alpha[r];

        // O += P V   (A-frag from Pw, B-frag from Vt)
        #pragma unroll
        for (int kks = 0; kks < 2; ++kks) {
            bf16x8 pa = *(const bf16x8*)(Pw + swz(lr, kks * 4 + lhi));
            #pragma unroll
            for (int n = 0; n < 4; ++n) {
                bf16x8 vb = *(const bf16x8*)(Vt + swz(n * 16 + lr, kks * 4 + lhi));
                acc[n] = __builtin_amdgcn_mfma_f32_16x16x32_bf16(pa, vb, acc[n], 0, 0, 0);
            }
        }
    }

    // epilogue: O /= l, write bf16 to [b, q, h, dh]
    #pragma unroll
    for (int r = 0; r < 4; ++r) {
        float inv = 1.0f / l_run[r];
        int qg = qt * 64 + w * 16 + lhi * 4 + r;
        size_t base = ((size_t)(b * 2048 + qg)) * 1024 + h * 64;
        #pragma unroll
        for (int n = 0; n < 4; ++n)
            out[base + n * 16 + lr] = f32_to_bf16(acc[n][r] * inv);
    }
}

extern "C" void kernel_launch(void* const* d_in, const int* in_sizes, int n_in,
                              void* d_out, int out_size, void* d_ws, size_t ws_size,
                              hipStream_t stream) {
    const float* x = (const float*)d_in[0];
    const float* w_in = (const float*)d_in[1];
    const float* b_in = (const float*)d_in[2];
    const float* w_out = (const float*)d_in[3];
    const float* b_out = (const float*)d_in[4];
    float* out = (float*)d_out;

    // workspace layout (bf16), 48 MB total
    u16* xb = (u16*)d_ws;                            // [4096][1024]
    u16* wib = xb + (size_t)4096 * 1024;             // [3072][1024]
    u16* wob = wib + (size_t)3072 * 1024;            // [1024][1024]
    u16* qkvb = wob + (size_t)1024 * 1024;           // [4096][3072]
    u16* attnb = qkvb + (size_t)4096 * 3072;         // [4096][1024]

    cvt_bf16<<<1024, 256, 0, stream>>>((const float4*)x, (uint2*)xb, 4096 * 1024 / 4);
    cvt_bf16<<<1024, 256, 0, stream>>>((const float4*)w_in, (uint2*)wib, 3072 * 1024 / 4);
    cvt_bf16<<<512, 256, 0, stream>>>((const float4*)w_out, (uint2*)wob, 1024 * 1024 / 4);

    // qkv = x @ w_in^T + b_in   -> bf16 [4096][3072]
    gemm_bt<true><<<dim3(32, 24), 256, 0, stream>>>(xb, wib, b_in, qkvb, 4096, 3072, 1024);
    // causal flash attention -> bf16 [4096][1024] (already [b,s,h,dh] = [b,s,d])
    attn_kernel<<<dim3(32, 16, 2), 256, 0, stream>>>(qkvb, attnb);
    // out = attn @ w_out^T + b_out -> f32
    gemm_bt<false><<<dim3(32, 8), 256, 0, stream>>>(attnb, wob, b_out, out, 4096, 1024, 1024);
}

// Round 2
// 193.198 us; speedup vs baseline: 1.3680x; 1.3680x over previous
//
#include <hip/hip_runtime.h>
#include <stdint.h>

typedef unsigned short u16;
typedef float f32x4 __attribute__((ext_vector_type(4)));
typedef __bf16 bf16x8 __attribute__((ext_vector_type(8)));

#define AS1 __attribute__((address_space(1)))
#define AS3 __attribute__((address_space(3)))

__device__ __forceinline__ u16 f32_to_bf16(float f) {
    unsigned u = __float_as_uint(f);
    unsigned r = u + 0x7fffu + ((u >> 16) & 1u);
    return (u16)(r >> 16);
}

__device__ __forceinline__ void gload_lds16(const u16* g, u16* l) {
    __builtin_amdgcn_global_load_lds((const AS1 unsigned int*)g,
                                     (AS3 unsigned int*)l, 16, 0, 0);
}

// element offset into a [rows][64]-u16 tile, XOR-swizzled at 16B-chunk granularity
__device__ __forceinline__ int swz(int row, int col8) {
    return row * 64 + (((col8 ^ (row & 7)) & 7) << 3);
}
// V-transpose swizzle: spreads the dh-column write collapse (dh>>3 folded in)
__device__ __forceinline__ int swzv(int row, int col8) {
    return row * 64 + (((col8 ^ row ^ (row >> 3)) & 7) << 3);
}
// P-scratch swizzle (16 rows): key uses row&7 and row-bit3 shifted to bit1
__device__ __forceinline__ int swzp(int row, int col8) {
    return row * 64 + (((col8 ^ (row & 7) ^ ((row >> 3) << 1)) & 7) << 3);
}

// ---------------- f32 -> bf16 convert (all three tensors in one launch) ----
__global__ __launch_bounds__(256) void cvt_bf16_3(const float4* __restrict__ in0,
                                                  const float4* __restrict__ in1,
                                                  const float4* __restrict__ in2,
                                                  uint2* __restrict__ out,
                                                  int n0, int n1, int ntot) {
    for (int i = blockIdx.x * blockDim.x + threadIdx.x; i < ntot;
         i += gridDim.x * blockDim.x) {
        float4 v;
        if (i < n0) v = in0[i];
        else if (i < n0 + n1) v = in1[i - n0];
        else v = in2[i - n0 - n1];
        uint2 o;
        o.x = (unsigned)f32_to_bf16(v.x) | ((unsigned)f32_to_bf16(v.y) << 16);
        o.y = (unsigned)f32_to_bf16(v.z) | ((unsigned)f32_to_bf16(v.w) << 16);
        out[i] = o;
    }
}

// ---------------- C[M,N] = A[M,K] * B[N,K]^T + bias ----------------
// A, B bf16 row-major with K contiguous. 128x128 tile, BK=64, 4 waves (2x2).
template <bool BF16_OUT>
__global__ __launch_bounds__(256) void gemm_bt(const u16* __restrict__ A,
                                               const u16* __restrict__ B,
                                               const float* __restrict__ bias,
                                               void* __restrict__ Cv,
                                               int M, int N, int K) {
    __shared__ u16 As[128 * 64];
    __shared__ u16 Bs[128 * 64];
    const int t = threadIdx.x;
    const int w = t >> 6, l = t & 63;
    const int lr = l & 15, lhi = l >> 4;
    const int wm = (w >> 1) * 64, wn = (w & 1) * 64;
    const int bm = blockIdx.x, bn = blockIdx.y;

    const u16* Ag = A + (size_t)bm * 128 * K;
    const u16* Bg = B + (size_t)bn * 128 * K;

    f32x4 acc[4][4] = {};

    for (int k0 = 0; k0 < K; k0 += 64) {
        #pragma unroll
        for (int i = 0; i < 4; ++i) {
            int c = i * 256 + t;
            int r = c >> 3, cl = c & 7;
            gload_lds16(Ag + (size_t)r * K + k0 + ((cl ^ (r & 7)) << 3), As + c * 8);
        }
        #pragma unroll
        for (int i = 0; i < 4; ++i) {
            int c = i * 256 + t;
            int r = c >> 3, cl = c & 7;
            gload_lds16(Bg + (size_t)r * K + k0 + ((cl ^ (r & 7)) << 3), Bs + c * 8);
        }
        __syncthreads();

        #pragma unroll
        for (int kks = 0; kks < 2; ++kks) {
            bf16x8 af[4], bfv[4];
            #pragma unroll
            for (int m = 0; m < 4; ++m)
                af[m] = *(const bf16x8*)(As + swz(wm + m * 16 + lr, kks * 4 + lhi));
            #pragma unroll
            for (int n = 0; n < 4; ++n)
                bfv[n] = *(const bf16x8*)(Bs + swz(wn + n * 16 + lr, kks * 4 + lhi));
            #pragma unroll
            for (int m = 0; m < 4; ++m)
                #pragma unroll
                for (int n = 0; n < 4; ++n)
                    acc[m][n] = __builtin_amdgcn_mfma_f32_16x16x32_bf16(
                        af[m], bfv[n], acc[m][n], 0, 0, 0);
        }
        __syncthreads();
    }

    const int row0 = bm * 128 + wm + lhi * 4;
    const int col0 = bn * 128 + wn + lr;
    #pragma unroll
    for (int n = 0; n < 4; ++n) {
        int col = col0 + n * 16;
        float bv = bias[col];
        #pragma unroll
        for (int m = 0; m < 4; ++m) {
            #pragma unroll
            for (int r = 0; r < 4; ++r) {
                int row = row0 + m * 16 + r;
                float v = acc[m][n][r] + bv;
                if constexpr (BF16_OUT)
                    ((u16*)Cv)[(size_t)row * N + col] = f32_to_bf16(v);
                else
                    ((float*)Cv)[(size_t)row * N + col] = v;
            }
        }
    }
}

// V-transpose write: thread owns rows (2g, 2g+1), cols cl*8..cl*8+7.
// Writes b32 pairs (kv-adjacent), 2-way bank conflict max.
__device__ __forceinline__ void write_vt(u16* vt, uint4 a, uint4 b, int g, int cl) {
    unsigned aw[4] = {a.x, a.y, a.z, a.w};
    unsigned bw[4] = {b.x, b.y, b.z, b.w};
    #pragma unroll
    for (int j = 0; j < 8; ++j) {
        int dh = cl * 8 + j;
        unsigned lo = (aw[j >> 1] >> ((j & 1) * 16)) & 0xffffu;
        unsigned hi = (bw[j >> 1] >> ((j & 1) * 16)) & 0xffffu;
        *(unsigned*)(vt + swzv(dh, g >> 2) + (2 * g & 7)) = lo | (hi << 16);
    }
}

// ---------------- causal flash attention ----------------
// qkv: [B*S][3072] bf16 (q|k|v each [.,H=16,Dh=64]); out: [B*S][1024] bf16
// grid: (S/64, H, B); 4 waves, wave w owns q rows [w*16, w*16+16).
// K/V double-buffered (2-phase pipeline, one barrier per KV tile).
__global__ __launch_bounds__(256, 4) void attn_kernel(const u16* __restrict__ qkv,
                                                      u16* __restrict__ out) {
    __shared__ u16 Ks[2][64 * 64];
    __shared__ u16 Vt[2][64 * 64];   // transposed: [dh][kv], swzv layout
    __shared__ u16 Qs[64 * 64];      // after prologue reused as per-wave P scratch
    const int t = threadIdx.x;
    const int w = t >> 6, l = t & 63;
    const int lr = l & 15, lhi = l >> 4;
    const int qt = blockIdx.x, h = blockIdx.y, b = blockIdx.z;

    const u16* Qg = qkv + ((size_t)(b * 2048 + qt * 64)) * 3072 + h * 64;
    const u16* Kg = qkv + ((size_t)(b * 2048)) * 3072 + 1024 + h * 64;
    const u16* Vg = qkv + ((size_t)(b * 2048)) * 3072 + 2048 + h * 64;

    const int vg = t >> 3, vcl = t & 7;  // V stage: rows 2vg,2vg+1, col chunk vcl

    // ---- prologue: stage Q, K0, V0 ----
    #pragma unroll
    for (int i = 0; i < 2; ++i) {
        int c = i * 256 + t, r = c >> 3, cl = c & 7;
        gload_lds16(Qg + (size_t)r * 3072 + ((cl ^ (r & 7)) << 3), Qs + c * 8);
    }
    #pragma unroll
    for (int i = 0; i < 2; ++i) {
        int c = i * 256 + t, r = c >> 3, cl = c & 7;
        gload_lds16(Kg + (size_t)r * 3072 + ((cl ^ (r & 7)) << 3), Ks[0] + c * 8);
    }
    uint4 va = *(const uint4*)(Vg + (size_t)(2 * vg) * 3072 + vcl * 8);
    uint4 vbr = *(const uint4*)(Vg + (size_t)(2 * vg + 1) * 3072 + vcl * 8);
    write_vt(Vt[0], va, vbr, vg, vcl);
    __syncthreads();

    bf16x8 qf[2];
    #pragma unroll
    for (int kks = 0; kks < 2; ++kks)
        qf[kks] = *(const bf16x8*)(Qs + swz(w * 16 + lr, kks * 4 + lhi));

    u16* Pw = Qs + w * 16 * 64;  // per-wave P scratch aliased on own Q rows
    f32x4 acc[4] = {};
    float m_run[4] = {-1e30f, -1e30f, -1e30f, -1e30f};
    float l_run[4] = {0.f, 0.f, 0.f, 0.f};
    const float SCALE = 0.125f * 1.44269504088896340736f;  // 1/sqrt(64)*log2(e)

    int cur = 0;
    for (int t64 = 0; t64 <= qt; ++t64) {
        const bool pf = (t64 < qt);
        if (pf) {  // issue next tile's loads first — they land during compute
            #pragma unroll
            for (int i = 0; i < 2; ++i) {
                int c = i * 256 + t, r = c >> 3, cl = c & 7;
                gload_lds16(Kg + ((size_t)((t64 + 1) * 64 + r)) * 3072 +
                                ((cl ^ (r & 7)) << 3),
                            Ks[cur ^ 1] + c * 8);
            }
            va = *(const uint4*)(Vg + ((size_t)((t64 + 1) * 64 + 2 * vg)) * 3072 + vcl * 8);
            vbr = *(const uint4*)(Vg + ((size_t)((t64 + 1) * 64 + 2 * vg + 1)) * 3072 + vcl * 8);
        }

        // S = Q K^T  (per wave: 16 q-rows x 64 kv)
        f32x4 sv[4] = {};
        #pragma unroll
        for (int kks = 0; kks < 2; ++kks) {
            #pragma unroll
            for (int n = 0; n < 4; ++n) {
                bf16x8 kf = *(const bf16x8*)(Ks[cur] + swz(n * 16 + lr, kks * 4 + lhi));
                sv[n] = __builtin_amdgcn_mfma_f32_16x16x32_bf16(qf[kks], kf, sv[n], 0, 0, 0);
            }
        }

        // scale + causal mask + row max (rows live on lanes sharing lhi,r)
        const bool diag = (t64 == qt);
        float mx[4] = {-1e30f, -1e30f, -1e30f, -1e30f};
        #pragma unroll
        for (int n = 0; n < 4; ++n)
            #pragma unroll
            for (int r = 0; r < 4; ++r) {
                float v = sv[n][r] * SCALE;
                if (diag && (n * 16 + lr) > (w * 16 + lhi * 4 + r)) v = -1e30f;
                sv[n][r] = v;
                mx[r] = fmaxf(mx[r], v);
            }
        #pragma unroll
        for (int off = 1; off < 16; off <<= 1)
            #pragma unroll
            for (int r = 0; r < 4; ++r)
                mx[r] = fmaxf(mx[r], __shfl_xor(mx[r], off, 64));

        float alpha[4], rs[4];
        #pragma unroll
        for (int r = 0; r < 4; ++r) {
            float mn = fmaxf(m_run[r], mx[r]);
            alpha[r] = exp2f(m_run[r] - mn);
            m_run[r] = mn;
            rs[r] = 0.f;
        }
        // P = exp2(s - m) -> per-wave LDS scratch in A-fragment layout
        #pragma unroll
        for (int n = 0; n < 4; ++n)
            #pragma unroll
            for (int r = 0; r < 4; ++r) {
                float p = exp2f(sv[n][r] - m_run[r]);
                rs[r] += p;
                int col = n * 16 + lr;
                Pw[swzp(lhi * 4 + r, (col >> 3)) + (col & 7)] = f32_to_bf16(p);
            }
        #pragma unroll
        for (int off = 1; off < 16; off <<= 1)
            #pragma unroll
            for (int r = 0; r < 4; ++r)
                rs[r] += __shfl_xor(rs[r], off, 64);
        #pragma unroll
        for (int r = 0; r < 4; ++r)
            l_run[r] = l_run[r] * alpha[r] + rs[r];
        #pragma unroll
        for (int n = 0; n < 4; ++n)
            #pragma unroll
            for (int r = 0; r < 4; ++r)
                acc[n][r] *= alpha[r];

        // O += P V
        #pragma unroll
        for (int kks = 0; kks < 2; ++kks) {
            bf16x8 pa = *(const bf16x8*)(Pw + swzp(lr, kks * 4 + lhi));
            #pragma unroll
            for (int n = 0; n < 4; ++n) {
                bf16x8 vb = *(const bf16x8*)(Vt[cur] + swzv(n * 16 + lr, kks * 4 + lhi));
                acc[n] = __builtin_amdgcn_mfma_f32_16x16x32_bf16(pa, vb, acc[n], 0, 0, 0);
            }
        }

        if (pf) write_vt(Vt[cur ^ 1], va, vbr, vg, vcl);  // waits on va/vbr regs only
        __syncthreads();  // drains prefetched gload_lds; flip buffers
        cur ^= 1;
    }

    // epilogue: O /= l, write bf16 to [b, q, h, dh]
    #pragma unroll
    for (int r = 0; r < 4; ++r) {
        float inv = 1.0f / l_run[r];
        int qg = qt * 64 + w * 16 + lhi * 4 + r;
        size_t base = ((size_t)(b * 2048 + qg)) * 1024 + h * 64;
        #pragma unroll
        for (int n = 0; n < 4; ++n)
            out[base + n * 16 + lr] = f32_to_bf16(acc[n][r] * inv);
    }
}

extern "C" void kernel_launch(void* const* d_in, const int* in_sizes, int n_in,
                              void* d_out, int out_size, void* d_ws, size_t ws_size,
                              hipStream_t stream) {
    const float* x = (const float*)d_in[0];
    const float* w_in = (const float*)d_in[1];
    const float* b_in = (const float*)d_in[2];
    const float* w_out = (const float*)d_in[3];
    const float* b_out = (const float*)d_in[4];
    float* out = (float*)d_out;

    // workspace layout (bf16), 48 MB total
    u16* xb = (u16*)d_ws;                            // [4096][1024]
    u16* wib = xb + (size_t)4096 * 1024;             // [3072][1024]
    u16* wob = wib + (size_t)3072 * 1024;            // [1024][1024]
    u16* qkvb = wob + (size_t)1024 * 1024;           // [4096][3072]
    u16* attnb = qkvb + (size_t)4096 * 3072;         // [4096][1024]

    // xb|wib|wob are contiguous: one convert launch for all three tensors
    const int n0 = 4096 * 1024 / 4, n1 = 3072 * 1024 / 4, n2 = 1024 * 1024 / 4;
    cvt_bf16_3<<<2048, 256, 0, stream>>>((const float4*)x, (const float4*)w_in,
                                         (const float4*)w_out, (uint2*)xb,
                                         n0, n1, n0 + n1 + n2);

    // qkv = x @ w_in^T + b_in   -> bf16 [4096][3072]
    gemm_bt<true><<<dim3(32, 24), 256, 0, stream>>>(xb, wib, b_in, qkvb, 4096, 3072, 1024);
    // causal flash attention -> bf16 [4096][1024] (already [b,s,h,dh] = [b,s,d])
    attn_kernel<<<dim3(32, 16, 2), 256, 0, stream>>>(qkvb, attnb);
    // out = attn @ w_out^T + b_out -> f32
    gemm_bt<false><<<dim3(32, 8), 256, 0, stream>>>(attnb, wob, b_out, out, 4096, 1024, 1024);
}

// Round 3
// 137.678 us; speedup vs baseline: 1.9197x; 1.4033x over previous
//
#include <hip/hip_runtime.h>
#include <stdint.h>

typedef unsigned short u16;
typedef float f32x4 __attribute__((ext_vector_type(4)));
typedef __bf16 bf16x8 __attribute__((ext_vector_type(8)));

#define AS1 __attribute__((address_space(1)))
#define AS3 __attribute__((address_space(3)))

__device__ __forceinline__ u16 f32_to_bf16(float f) {
    unsigned u = __float_as_uint(f);
    unsigned r = u + 0x7fffu + ((u >> 16) & 1u);
    return (u16)(r >> 16);
}

__device__ __forceinline__ void gload_lds16(const u16* g, u16* l) {
    __builtin_amdgcn_global_load_lds((const AS1 unsigned int*)g,
                                     (AS3 unsigned int*)l, 16, 0, 0);
}

// element offset into a [rows][64]-u16 tile, XOR-swizzled at 16B-chunk granularity
__device__ __forceinline__ int swz(int row, int col8) {
    return row * 64 + (((col8 ^ (row & 7)) & 7) << 3);
}
// V-transpose swizzle: spreads the dh-column write collapse (dh>>3 folded in)
__device__ __forceinline__ int swzv(int row, int col8) {
    return row * 64 + (((col8 ^ row ^ (row >> 3)) & 7) << 3);
}

// ---------------- f32 -> bf16 convert (all three tensors in one launch) ----
__global__ __launch_bounds__(256) void cvt_bf16_3(const float4* __restrict__ in0,
                                                  const float4* __restrict__ in1,
                                                  const float4* __restrict__ in2,
                                                  uint2* __restrict__ out,
                                                  int n0, int n1, int ntot) {
    for (int i = blockIdx.x * blockDim.x + threadIdx.x; i < ntot;
         i += gridDim.x * blockDim.x) {
        float4 v;
        if (i < n0) v = in0[i];
        else if (i < n0 + n1) v = in1[i - n0];
        else v = in2[i - n0 - n1];
        uint2 o;
        o.x = (unsigned)f32_to_bf16(v.x) | ((unsigned)f32_to_bf16(v.y) << 16);
        o.y = (unsigned)f32_to_bf16(v.z) | ((unsigned)f32_to_bf16(v.w) << 16);
        out[i] = o;
    }
}

// ---------------- C[M,N] = A[M,K] * B[N,K]^T + bias ----------------
template <bool BF16_OUT>
__global__ __launch_bounds__(256) void gemm_bt(const u16* __restrict__ A,
                                               const u16* __restrict__ B,
                                               const float* __restrict__ bias,
                                               void* __restrict__ Cv,
                                               int M, int N, int K) {
    __shared__ u16 As[128 * 64];
    __shared__ u16 Bs[128 * 64];
    const int t = threadIdx.x;
    const int w = t >> 6, l = t & 63;
    const int lr = l & 15, lhi = l >> 4;
    const int wm = (w >> 1) * 64, wn = (w & 1) * 64;
    const int bm = blockIdx.x, bn = blockIdx.y;

    const u16* Ag = A + (size_t)bm * 128 * K;
    const u16* Bg = B + (size_t)bn * 128 * K;

    f32x4 acc[4][4] = {};

    for (int k0 = 0; k0 < K; k0 += 64) {
        #pragma unroll
        for (int i = 0; i < 4; ++i) {
            int c = i * 256 + t;
            int r = c >> 3, cl = c & 7;
            gload_lds16(Ag + (size_t)r * K + k0 + ((cl ^ (r & 7)) << 3), As + c * 8);
        }
        #pragma unroll
        for (int i = 0; i < 4; ++i) {
            int c = i * 256 + t;
            int r = c >> 3, cl = c & 7;
            gload_lds16(Bg + (size_t)r * K + k0 + ((cl ^ (r & 7)) << 3), Bs + c * 8);
        }
        __syncthreads();

        #pragma unroll
        for (int kks = 0; kks < 2; ++kks) {
            bf16x8 af[4], bfv[4];
            #pragma unroll
            for (int m = 0; m < 4; ++m)
                af[m] = *(const bf16x8*)(As + swz(wm + m * 16 + lr, kks * 4 + lhi));
            #pragma unroll
            for (int n = 0; n < 4; ++n)
                bfv[n] = *(const bf16x8*)(Bs + swz(wn + n * 16 + lr, kks * 4 + lhi));
            #pragma unroll
            for (int m = 0; m < 4; ++m)
                #pragma unroll
                for (int n = 0; n < 4; ++n)
                    acc[m][n] = __builtin_amdgcn_mfma_f32_16x16x32_bf16(
                        af[m], bfv[n], acc[m][n], 0, 0, 0);
        }
        __syncthreads();
    }

    const int row0 = bm * 128 + wm + lhi * 4;
    const int col0 = bn * 128 + wn + lr;
    #pragma unroll
    for (int n = 0; n < 4; ++n) {
        int col = col0 + n * 16;
        float bv = bias[col];
        #pragma unroll
        for (int m = 0; m < 4; ++m) {
            #pragma unroll
            for (int r = 0; r < 4; ++r) {
                int row = row0 + m * 16 + r;
                float v = acc[m][n][r] + bv;
                if constexpr (BF16_OUT)
                    ((u16*)Cv)[(size_t)row * N + col] = f32_to_bf16(v);
                else
                    ((float*)Cv)[(size_t)row * N + col] = v;
            }
        }
    }
}

// V-transpose write: thread owns rows (2g, 2g+1), cols cl*8..cl*8+7.
__device__ __forceinline__ void write_vt(u16* vt, uint4 a, uint4 b, int g, int cl) {
    unsigned aw[4] = {a.x, a.y, a.z, a.w};
    unsigned bw[4] = {b.x, b.y, b.z, b.w};
    #pragma unroll
    for (int j = 0; j < 8; ++j) {
        int dh = cl * 8 + j;
        unsigned lo = (aw[j >> 1] >> ((j & 1) * 16)) & 0xffffu;
        unsigned hi = (bw[j >> 1] >> ((j & 1) * 16)) & 0xffffu;
        *(unsigned*)(vt + swzv(dh, g >> 2) + (2 * g & 7)) = lo | (hi << 16);
    }
}

// ---------------- causal flash attention (balanced, swapped-QK softmax) ----
// qkv: [B*S][3072] bf16; out: [B*S][1024] bf16
// grid: (16, H, B); block bi processes q-tiles {bi, 31-bi} -> uniform 33 KV iters.
// Swapped QK^T: S^T = mfma(K, Q) puts q = lane&15 -> per-lane scalar m/l state.
__global__ __launch_bounds__(256, 4) void attn_kernel(const u16* __restrict__ qkv,
                                                      u16* __restrict__ out) {
    __shared__ u16 Ks[2][64 * 64];
    __shared__ u16 Vt[2][64 * 64];   // transposed: [dh][kv], swzv layout
    __shared__ u16 Qs[64 * 64];      // after qf load, reused as per-wave P scratch
    const int t = threadIdx.x;
    const int w = t >> 6, l = t & 63;
    const int lr = l & 15, lhi = l >> 4;
    const int bi = blockIdx.x, h = blockIdx.y, b = blockIdx.z;

    const u16* Kg = qkv + ((size_t)(b * 2048)) * 3072 + 1024 + h * 64;
    const u16* Vg = qkv + ((size_t)(b * 2048)) * 3072 + 2048 + h * 64;
    const int vg = t >> 3, vcl = t & 7;
    const float SCALE = 0.125f * 1.44269504088896340736f;  // 1/sqrt(64)*log2(e)

    #pragma unroll 1
    for (int pass = 0; pass < 2; ++pass) {
        const int qt = pass ? (31 - bi) : bi;
        const u16* Qg = qkv + ((size_t)(b * 2048 + qt * 64)) * 3072 + h * 64;
        __syncthreads();
        // prologue: stage Q, K0, V0
        #pragma unroll
        for (int i = 0; i < 2; ++i) {
            int c = i * 256 + t, r = c >> 3, cl = c & 7;
            gload_lds16(Qg + (size_t)r * 3072 + ((cl ^ (r & 7)) << 3), Qs + c * 8);
            gload_lds16(Kg + (size_t)r * 3072 + ((cl ^ (r & 7)) << 3), Ks[0] + c * 8);
        }
        uint4 va = *(const uint4*)(Vg + (size_t)(2 * vg) * 3072 + vcl * 8);
        uint4 vbr = *(const uint4*)(Vg + (size_t)(2 * vg + 1) * 3072 + vcl * 8);
        write_vt(Vt[0], va, vbr, vg, vcl);
        __syncthreads();

        bf16x8 qf[2];
        qf[0] = *(const bf16x8*)(Qs + swz(w * 16 + lr, lhi));
        qf[1] = *(const bf16x8*)(Qs + swz(w * 16 + lr, 4 + lhi));

        u16* Pw = Qs + w * 16 * 64;       // wave-private: exactly this wave's Q rows
        unsigned* Pst = (unsigned*)Pw;
        f32x4 acc[4] = {};
        float m_run = -1e30f, l_run = 0.f;  // per-lane state for q-row = lr
        int cur = 0;

        for (int t64 = 0; t64 <= qt; ++t64) {
            const bool pf = (t64 < qt);
            if (pf) {  // issue next tile's loads first — land during compute
                #pragma unroll
                for (int i = 0; i < 2; ++i) {
                    int c = i * 256 + t, r = c >> 3, cl = c & 7;
                    gload_lds16(Kg + ((size_t)((t64 + 1) * 64 + r)) * 3072 +
                                    ((cl ^ (r & 7)) << 3),
                                Ks[cur ^ 1] + c * 8);
                }
                va = *(const uint4*)(Vg + ((size_t)((t64 + 1) * 64 + 2 * vg)) * 3072 + vcl * 8);
                vbr = *(const uint4*)(Vg + ((size_t)((t64 + 1) * 64 + 2 * vg + 1)) * 3072 + vcl * 8);
            }

            // S^T = K Q^T: sv[n] rows kv = n*16+lhi*4+r, col q = lr
            f32x4 sv[4] = {};
            __builtin_amdgcn_s_setprio(1);
            #pragma unroll
            for (int kks = 0; kks < 2; ++kks) {
                #pragma unroll
                for (int n = 0; n < 4; ++n) {
                    bf16x8 kf = *(const bf16x8*)(Ks[cur] + swz(n * 16 + lr, kks * 4 + lhi));
                    sv[n] = __builtin_amdgcn_mfma_f32_16x16x32_bf16(kf, qf[kks], sv[n], 0, 0, 0);
                }
            }
            __builtin_amdgcn_s_setprio(0);

            // scale + causal mask + in-thread max (this lane's 16 kv for q=lr)
            const bool diag = (t64 == qt);
            float mx = -1e30f;
            #pragma unroll
            for (int n = 0; n < 4; ++n)
                #pragma unroll
                for (int r = 0; r < 4; ++r) {
                    float v = sv[n][r] * SCALE;
                    if (diag && (n * 16 + lhi * 4 + r) > (w * 16 + lr)) v = -1e30f;
                    sv[n][r] = v;
                    mx = fmaxf(mx, v);
                }
            // reduce over the 4 lhi-groups -> full row max for q=lr
            mx = fmaxf(mx, __shfl_xor(mx, 16, 64));
            mx = fmaxf(mx, __shfl_xor(mx, 32, 64));

            // defer-max (THR=8): only rescale when the running max grew a lot
            if (__any(mx > m_run + 8.f)) {
                float mn = fmaxf(m_run, mx);
                float alpha = exp2f(m_run - mn);
                m_run = mn;
                l_run *= alpha;
                #pragma unroll
                for (int r = 0; r < 4; ++r) {
                    float ar = __shfl(alpha, lhi * 4 + r, 16);  // alpha of q=lhi*4+r
                    #pragma unroll
                    for (int n = 0; n < 4; ++n) acc[n][r] *= ar;
                }
            }

            // P = exp2(S - m), in-thread partial sum
            float rs = 0.f;
            #pragma unroll
            for (int n = 0; n < 4; ++n)
                #pragma unroll
                for (int r = 0; r < 4; ++r) {
                    float p = exp2f(sv[n][r] - m_run);
                    sv[n][r] = p;
                    rs += p;
                }
            rs += __shfl_xor(rs, 16, 64);
            rs += __shfl_xor(rs, 32, 64);
            l_run += rs;

            // pack kv-adjacent pairs -> u32, store to wave-private A-frag scratch
            #pragma unroll
            for (int n = 0; n < 4; ++n)
                #pragma unroll
                for (int rp = 0; rp < 2; ++rp) {
                    union { unsigned u; __bf16 h[2]; } pk;
                    pk.h[0] = (__bf16)sv[n][2 * rp];
                    pk.h[1] = (__bf16)sv[n][2 * rp + 1];
                    int p = 8 * n + 2 * lhi + rp;  // kv-pair index, row q=lr
                    Pst[lr * 32 + (((p >> 2) ^ (lr & 7)) << 2) + (p & 3)] = pk.u;
                }

            // O += P V (pa: row q=lr, kv-chunk lhi; no barrier — wave-private)
            __builtin_amdgcn_s_setprio(1);
            #pragma unroll
            for (int kks = 0; kks < 2; ++kks) {
                bf16x8 pa = *(const bf16x8*)(Pw + lr * 64 +
                                             (((kks * 4 + lhi) ^ (lr & 7)) << 3));
                #pragma unroll
                for (int n = 0; n < 4; ++n) {
                    bf16x8 vb = *(const bf16x8*)(Vt[cur] + swzv(n * 16 + lr, kks * 4 + lhi));
                    acc[n] = __builtin_amdgcn_mfma_f32_16x16x32_bf16(pa, vb, acc[n], 0, 0, 0);
                }
            }
            __builtin_amdgcn_s_setprio(0);

            if (pf) write_vt(Vt[cur ^ 1], va, vbr, vg, vcl);
            __syncthreads();
            cur ^= 1;
        }

        // epilogue: O /= l (l of q=lhi*4+r via shfl), write bf16 [b,q,h,dh]
        float rinv = 1.0f / l_run;
        #pragma unroll
        for (int r = 0; r < 4; ++r) {
            float ir = __shfl(rinv, lhi * 4 + r, 16);
            int qg = qt * 64 + w * 16 + lhi * 4 + r;
            size_t base = ((size_t)(b * 2048 + qg)) * 1024 + h * 64;
            #pragma unroll
            for (int n = 0; n < 4; ++n)
                out[base + n * 16 + lr] = f32_to_bf16(acc[n][r] * ir);
        }
    }
}

extern "C" void kernel_launch(void* const* d_in, const int* in_sizes, int n_in,
                              void* d_out, int out_size, void* d_ws, size_t ws_size,
                              hipStream_t stream) {
    const float* x = (const float*)d_in[0];
    const float* w_in = (const float*)d_in[1];
    const float* b_in = (const float*)d_in[2];
    const float* w_out = (const float*)d_in[3];
    const float* b_out = (const float*)d_in[4];
    float* out = (float*)d_out;

    // workspace layout (bf16), 48 MB total
    u16* xb = (u16*)d_ws;                            // [4096][1024]
    u16* wib = xb + (size_t)4096 * 1024;             // [3072][1024]
    u16* wob = wib + (size_t)3072 * 1024;            // [1024][1024]
    u16* qkvb = wob + (size_t)1024 * 1024;           // [4096][3072]
    u16* attnb = qkvb + (size_t)4096 * 3072;         // [4096][1024]

    const int n0 = 4096 * 1024 / 4, n1 = 3072 * 1024 / 4, n2 = 1024 * 1024 / 4;
    cvt_bf16_3<<<2048, 256, 0, stream>>>((const float4*)x, (const float4*)w_in,
                                         (const float4*)w_out, (uint2*)xb,
                                         n0, n1, n0 + n1 + n2);

    // qkv = x @ w_in^T + b_in   -> bf16 [4096][3072]
    gemm_bt<true><<<dim3(32, 24), 256, 0, stream>>>(xb, wib, b_in, qkvb, 4096, 3072, 1024);
    // causal flash attention -> bf16 [4096][1024]
    attn_kernel<<<dim3(16, 16, 2), 256, 0, stream>>>(qkvb, attnb);
    // out = attn @ w_out^T + b_out -> f32
    gemm_bt<false><<<dim3(32, 8), 256, 0, stream>>>(attnb, wob, b_out, out, 4096, 1024, 1024);
}